// Round 1
// baseline (32.649 us; speedup 1.0000x reference)
//
#include <hip/hip_runtime.h>
#include <hip/hip_bf16.h>

// YOLO-style detector decode, 3 scales.
// Scale s: input [B=32, C=255=3*85, H, W], H=W in {13,26,52}
// Output row r (global, concatenated over scales) = 6 floats:
//   [conf, x1, y1, x2, y2, cls]  or all-zero if conf <= thresh.
// Row ordering within a scale: ((b*H+h)*W+w)*3 + a  (matches reshape(-1,6)).

#define NUM_B 32
#define NUM_CLS 80
#define CH 255

// rows per scale
#define R13 (NUM_B * 13 * 13 * 3)            // 16224
#define R26 (NUM_B * 26 * 26 * 3)            // 64896
#define R52 (NUM_B * 52 * 52 * 3)            // 259584
#define CUM13 R13                             // 16224
#define CUM26 (R13 + R26)                     // 81120
#define TOTAL (R13 + R26 + R52)               // 340704

__global__ __launch_bounds__(256) void detector_decode(
    const float* __restrict__ in13,
    const float* __restrict__ in26,
    const float* __restrict__ in52,
    const float* __restrict__ anchors,   // [3,3,2] flat
    float* __restrict__ out)             // [TOTAL, 6] flat
{
    int tid = blockIdx.x * blockDim.x + threadIdx.x;
    if (tid >= TOTAL) return;

    const float* in;
    int H;
    float thresh, step;
    int aoff;   // anchors offset for this scale (s*6)
    int r;      // row index within scale
    if (tid < CUM13) {
        in = in13; H = 13; thresh = 0.5f; step = 32.0f; aoff = 0; r = tid;
    } else if (tid < CUM26) {
        in = in26; H = 26; thresh = 0.5f; step = 16.0f; aoff = 6; r = tid - CUM13;
    } else {
        in = in52; H = 52; thresh = 0.9f; step = 8.0f;  aoff = 12; r = tid - CUM26;
    }

    const int W  = H;
    const int HW = H * W;

    const int a    = r % 3;
    const int cell = r / 3;
    const int hw   = cell % HW;
    const int b    = cell / HW;

    // base of this (b, anchor) slab; channel stride = HW
    const float* p = in + ((size_t)b * CH + (size_t)a * 85) * (size_t)HW + hw;

    float* o = out + (size_t)tid * 6;

    const float conf = p[0];
    if (!(conf > thresh)) {
        // masked row -> all zeros (d_out is poisoned, must write)
        o[0] = 0.0f; o[1] = 0.0f; o[2] = 0.0f;
        o[3] = 0.0f; o[4] = 0.0f; o[5] = 0.0f;
        return;
    }

    const float tx = p[(size_t)1 * HW];
    const float ty = p[(size_t)2 * HW];
    const float tw = p[(size_t)3 * HW];
    const float th = p[(size_t)4 * HW];

    const int wi = hw % W;
    const int hi = hw / W;

    const float cx = ((float)wi + tx) * step;
    const float cy = ((float)hi + ty) * step;
    const float aw = anchors[aoff + a * 2 + 0] * __expf(tw) ;
    const float ah = anchors[aoff + a * 2 + 1] * __expf(th) ;
    // NOTE: __expf is ~2 ulp; threshold is 10.24 absolute so fine, but use
    // expf for safety on large magnitudes? exp(|t|<~5) -> <150, rel err of
    // __expf ~1e-5 -> abs err ~1e-3. OK.

    const float x1 = cx - aw * 0.5f;
    const float y1 = cy - ah * 0.5f;
    const float x2 = x1 + aw;
    const float y2 = y1 + ah;

    // argmax over 80 classes, first-max-wins (strict >)
    const float* pc = p + (size_t)5 * HW;
    float best = pc[0];
    int bi = 0;
    #pragma unroll 8
    for (int c = 1; c < NUM_CLS; ++c) {
        float v = pc[(size_t)c * HW];
        if (v > best) { best = v; bi = c; }
    }

    o[0] = conf;
    o[1] = x1;
    o[2] = y1;
    o[3] = x2;
    o[4] = y2;
    o[5] = (float)bi;
}

extern "C" void kernel_launch(void* const* d_in, const int* in_sizes, int n_in,
                              void* d_out, int out_size, void* d_ws, size_t ws_size,
                              hipStream_t stream) {
    const float* in13    = (const float*)d_in[0];
    const float* in26    = (const float*)d_in[1];
    const float* in52    = (const float*)d_in[2];
    const float* anchors = (const float*)d_in[3];
    float* out = (float*)d_out;

    const int threads = 256;
    const int blocks  = (TOTAL + threads - 1) / threads;
    detector_decode<<<blocks, threads, 0, stream>>>(in13, in26, in52, anchors, out);
}